// Round 2
// baseline (236.234 us; speedup 1.0000x reference)
//
#include <hip/hip_runtime.h>

#define NB 8
#define NC 256
#define NL 2048
#define SCALE 0.0625f   // C^-0.5 = 1/16

typedef __attribute__((ext_vector_type(8))) __bf16 bf16x8;
typedef __attribute__((ext_vector_type(4))) float f32x4;
typedef __attribute__((ext_vector_type(4))) unsigned int u32x4;
typedef __attribute__((ext_vector_type(4))) unsigned short u16x4;
typedef __attribute__((ext_vector_type(8))) unsigned short u16x8;

// round-to-nearest-even fp32 -> bf16 bits
static __device__ __forceinline__ unsigned short f2b(float f) {
    unsigned int u = __builtin_bit_cast(unsigned int, f);
    u += 0x7fffu + ((u >> 16) & 1u);
    return (unsigned short)(u >> 16);
}

// ---------------------------------------------------------------------------
// Prep A: Wq/Wk/Wv fp32 -> bf16, concatenated [3][256][256].
// ---------------------------------------------------------------------------
__global__ void wconv_kernel(const float* __restrict__ Wq,
                             const float* __restrict__ Wk,
                             const float* __restrict__ Wv,
                             unsigned short* __restrict__ Wbf)
{
    const int base = (blockIdx.x * 256 + threadIdx.x) * 4;
    const int mat  = base >> 16;
    const int off  = base & 65535;
    const float* W = (mat == 0) ? Wq : (mat == 1) ? Wk : Wv;
    float4 w = *(const float4*)&W[off];
    u16x4 p = {f2b(w.x), f2b(w.y), f2b(w.z), f2b(w.w)};
    *(u16x4*)&Wbf[base] = p;
}

// ---------------------------------------------------------------------------
// Prep B: x [B][C][L] fp32 -> xT [B][L][C] bf16 (transpose via LDS).
// ---------------------------------------------------------------------------
__global__ __launch_bounds__(256, 2) void xprep_kernel(
    const float* __restrict__ x, unsigned short* __restrict__ xT)
{
    const int b  = blockIdx.z;
    const int c0 = blockIdx.y * 64;
    const int l0 = blockIdx.x * 64;
    const int t  = threadIdx.x;

    __shared__ unsigned short Tr[64][68];

    #pragma unroll
    for (int p = 0; p < 4; ++p) {
        const int c  = p * 16 + (t >> 4);
        const int lg = t & 15;
        float4 xv = *(const float4*)&x[((size_t)(b * NC + c0 + c)) * NL + l0 + lg * 4];
        u16x4 pk = {f2b(xv.x), f2b(xv.y), f2b(xv.z), f2b(xv.w)};
        *(u16x4*)&Tr[c][lg * 4] = pk;
    }
    __syncthreads();
    #pragma unroll
    for (int j = 0; j < 2; ++j) {
        const int chunk = t + 256 * j;      // 0..511
        const int l  = chunk >> 3;
        const int ck = chunk & 7;
        u16x8 o;
        #pragma unroll
        for (int i = 0; i < 8; ++i) o[i] = Tr[ck * 8 + i][l];
        *(u16x8*)&xT[((size_t)(b * NL + l0 + l)) * NC + c0 + ck * 8] = o;
    }
}

// ---------------------------------------------------------------------------
// Kernel 1: QKV projection via MFMA (verbatim from verified state).
// ---------------------------------------------------------------------------
__global__ __launch_bounds__(256, 2) void qkv_mfma(
    const unsigned short* __restrict__ xT,
    const unsigned short* __restrict__ Wbf,
    const float* __restrict__ bq, const float* __restrict__ bk,
    const float* __restrict__ bv,
    unsigned short* __restrict__ qT, unsigned short* __restrict__ kT,
    unsigned short* __restrict__ vo)
{
    const int raw = blockIdx.x;
    const int b   = raw & 7;          // XCD-pinned batch
    const int rem = raw >> 3;         // 0..95
    const int mat = rem >> 5;         // 0..2
    const int lt0 = (rem & 31) * 64;
    const int t    = threadIdx.x;
    const int w    = t >> 6;
    const int lane = t & 63;
    const int ln15 = lane & 15;
    const int quad = lane >> 4;

    __shared__ __align__(16) unsigned short XT[64 * 256];  // [l][c] swz, 32 KB
    __shared__ __align__(16) unsigned short WC[256 * 64];  // [o][c-chunk] swz, 32 KB

    const unsigned short* Wm = Wbf + mat * 65536;
    const float* bias = (mat == 0) ? bq : (mat == 1) ? bk : bv;

    float bvals[4][4];
    #pragma unroll
    for (int ot = 0; ot < 4; ++ot)
        #pragma unroll
        for (int r = 0; r < 4; ++r)
            bvals[ot][r] = bias[w * 64 + ot * 16 + quad * 4 + r];

    #pragma unroll
    for (int s = 0; s < 8; ++s) {
        const int il = w * 8 + s;
        const int n  = il * 2 + (lane >> 5);
        const int p  = lane & 31;
        const int g  = p ^ (n & 15);
        const unsigned short* gp = &xT[((size_t)(b * NL + lt0 + n)) * NC + g * 8];
        __builtin_amdgcn_global_load_lds(
            (const __attribute__((address_space(1))) unsigned int*)gp,
            (__attribute__((address_space(3))) unsigned int*)&XT[il * 512],
            16, 0, 0);
    }

    f32x4 acc[4][4];
    #pragma unroll
    for (int i = 0; i < 4; ++i)
        #pragma unroll
        for (int j = 0; j < 4; ++j) acc[i][j] = f32x4{0.f, 0.f, 0.f, 0.f};

    for (int k0 = 0; k0 < 4; ++k0) {
        if (k0) __syncthreads();
        #pragma unroll
        for (int s = 0; s < 8; ++s) {
            const int il = w * 8 + s;
            const int o  = il * 8 + (lane >> 3);
            const int p  = lane & 7;
            const int g  = p ^ (o & 7);
            const unsigned short* gp = &Wm[(size_t)o * NC + k0 * 64 + g * 8];
            __builtin_amdgcn_global_load_lds(
                (const __attribute__((address_space(1))) unsigned int*)gp,
                (__attribute__((address_space(3))) unsigned int*)&WC[il * 512],
                16, 0, 0);
        }
        __syncthreads();

        #pragma unroll
        for (int ks = 0; ks < 2; ++ks) {
            bf16x8 xf[4];
            #pragma unroll
            for (int lt = 0; lt < 4; ++lt) {
                const int l  = lt * 16 + ln15;
                const int kc = k0 * 8 + ks * 4 + quad;
                const int pp = kc ^ (l & 15);
                xf[lt] = __builtin_bit_cast(bf16x8, *(const u32x4*)&XT[l * 256 + pp * 8]);
            }
            #pragma unroll
            for (int ot = 0; ot < 4; ++ot) {
                const int o  = w * 64 + ot * 16 + ln15;
                const int pp = (ks * 4 + quad) ^ (o & 7);
                bf16x8 wf = __builtin_bit_cast(bf16x8, *(const u32x4*)&WC[o * 64 + pp * 8]);
                #pragma unroll
                for (int lt = 0; lt < 4; ++lt)
                    acc[ot][lt] = __builtin_amdgcn_mfma_f32_16x16x32_bf16(
                                      wf, xf[lt], acc[ot][lt], 0, 0, 0);
            }
        }
    }

    if (mat < 2) {
        unsigned short* out = (mat == 0) ? qT : kT;
        #pragma unroll
        for (int ot = 0; ot < 4; ++ot) {
            const int o_base = w * 64 + ot * 16 + quad * 4;
            #pragma unroll
            for (int lt = 0; lt < 4; ++lt) {
                const int l = lt0 + lt * 16 + ln15;
                u16x4 pk;
                #pragma unroll
                for (int r = 0; r < 4; ++r)
                    pk[r] = f2b(acc[ot][lt][r] + bvals[ot][r]);
                *(u16x4*)&out[((size_t)(b * NL + l)) * NC + o_base] = pk;
            }
        }
    } else {
        #pragma unroll
        for (int ot = 0; ot < 4; ++ot)
            #pragma unroll
            for (int lt = 0; lt < 4; ++lt) {
                const int l = lt0 + lt * 16 + ln15;
                #pragma unroll
                for (int r = 0; r < 4; ++r) {
                    const int o = w * 64 + ot * 16 + quad * 4 + r;
                    vo[((size_t)(b * NC + o)) * NL + l] = f2b(acc[ot][lt][r] + bvals[ot][r]);
                }
            }
    }
}

// ---------------------------------------------------------------------------
// Kernel 2: MFMA flash attention + residual.
// grid 256 (b=raw&7, 32 l-tiles), block 1024 = 16 waves (qg 0..3 x kg 0..3)
// -> 4 waves/SIMD (was 2). Same dbuf K/V staging & swizzles; ONE barrier per
// key tile. Per wave: 16 q x 16 keys. QK = 16x16x32 chain-8 (unchanged).
// PV + denominator use ONLY the verified mfma_f32_16x16x32_bf16: the K=32
// window is the kg-PAIR's 32 keys, and the P (A-operand) fragment is
// zero-selected on the quads that belong to the other wave's 16 keys, so
// each wave still contributes exactly its own keys. Softmax denominator is
// one extra MFMA against a ones fragment (row-sum of P). Epilogue combines
// the 4 kg quarters via LDS.
// ---------------------------------------------------------------------------
__global__ __launch_bounds__(1024, 4) void attn_kernel(
    const unsigned short* __restrict__ qT,
    const unsigned short* __restrict__ kT,
    const unsigned short* __restrict__ v,
    const float* __restrict__ x,
    float* __restrict__ out)
{
    const int raw  = blockIdx.x;
    const int b    = raw & 7;         // XCD-pinned batch
    const int l0   = (raw >> 3) * 64;
    const int t    = threadIdx.x;
    const int w    = t >> 6;          // 0..15
    const int lane = t & 63;
    const int ln15 = lane & 15;
    const int quad = lane >> 4;
    const int qg   = w & 3;           // query group (16 rows)
    const int kg   = w >> 2;          // key quarter (16 keys)
    const int kp   = kg >> 1;         // key pair (32-key MFMA window)

    __shared__ __align__(16) char smem[140288];
    unsigned short* Kb0 = (unsigned short*)smem;             // 32 KB
    unsigned short* Kb1 = (unsigned short*)(smem + 32768);   // 32 KB
    unsigned short* Vb0 = (unsigned short*)(smem + 65536);   // 32 KB
    unsigned short* Vb1 = (unsigned short*)(smem + 98304);   // 32 KB
    unsigned short* Plds = (unsigned short*)(smem + 131072); //  8 KB [64q][64j] swz
    float* denomP = (float*)(smem + 139264);                 // 4*64 f32
    float (*bufA)[68] = (float(*)[68])smem;                  // epilogue alias
    float (*bufB)[68] = (float(*)[68])(smem + 69632);        // epilogue alias

    // ---- Q fragments resident: rows l0 + qg*16 + ln15 ----
    bf16x8 qf[8];
    {
        const size_t qrow = ((size_t)b * NL + l0 + qg * 16 + ln15) * NC;
        #pragma unroll
        for (int kt = 0; kt < 8; ++kt)
            qf[kt] = __builtin_bit_cast(bf16x8,
                        *(const u32x4*)&qT[qrow + kt * 32 + quad * 8]);
    }

    f32x4 ctx[16];
    #pragma unroll
    for (int i = 0; i < 16; ++i) ctx[i] = f32x4{0.f, 0.f, 0.f, 0.f};
    f32x4 dacc = f32x4{0.f, 0.f, 0.f, 0.f};

    const u16x8 ones_u = {0x3F80, 0x3F80, 0x3F80, 0x3F80,
                          0x3F80, 0x3F80, 0x3F80, 0x3F80};
    const bf16x8 onesf = __builtin_bit_cast(bf16x8, ones_u);

    // live: this lane's K-slice (quad*8..quad*8+7 of the 32-key window)
    // belongs to THIS wave's 16 keys.
    const bool live = ((quad >> 1) == (kg & 1));

    auto stage = [&](int mt, unsigned short* Kd, unsigned short* Vd) {
        const int m0 = mt * 64;
        #pragma unroll
        for (int s = 0; s < 2; ++s) {
            const int il = w * 2 + s;
            const int n  = il * 2 + (lane >> 5);
            const int g  = (lane & 31) ^ (n & 15);
            const unsigned short* gp = &kT[((size_t)b * NL + m0 + n) * NC + g * 8];
            __builtin_amdgcn_global_load_lds(
                (const __attribute__((address_space(1))) unsigned int*)gp,
                (__attribute__((address_space(3))) unsigned int*)&Kd[il * 512],
                16, 0, 0);
        }
        #pragma unroll
        for (int s = 0; s < 2; ++s) {
            const int il = w * 2 + s;
            const int c  = il * 8 + (lane >> 3);
            const int g  = (lane & 7) ^ (c & 7);
            const unsigned short* gp = &v[((size_t)(b * NC + c)) * NL + m0 + g * 8];
            __builtin_amdgcn_global_load_lds(
                (const __attribute__((address_space(1))) unsigned int*)gp,
                (__attribute__((address_space(3))) unsigned int*)&Vd[il * 512],
                16, 0, 0);
        }
    };

    stage(0, Kb0, Vb0);
    __syncthreads();   // buf0 ready

    for (int mt = 0; mt < 32; ++mt) {
        // prefetch next tile into the other buffer (overlaps compute below)
        if (mt < 31) {
            if (mt & 1) stage(mt + 1, Kb0, Vb0);
            else        stage(mt + 1, Kb1, Vb1);
        }
        const unsigned short* Kd = (mt & 1) ? Kb1 : Kb0;
        const unsigned short* Vd = (mt & 1) ? Vb1 : Vb0;

        // ---- S = Q^T K (this wave: 16 q x 16 keys of quarter kg) ----
        f32x4 sacc = f32x4{0.f, 0.f, 0.f, 0.f};
        const int n = kg * 16 + ln15;
        #pragma unroll
        for (int kt = 0; kt < 8; ++kt) {
            const int p = (kt * 4 + quad) ^ ln15;
            bf16x8 bf = __builtin_bit_cast(bf16x8,
                          *(const u32x4*)&Kd[n * 256 + p * 8]);
            sacc = __builtin_amdgcn_mfma_f32_16x16x32_bf16(
                       qf[kt], bf, sacc, 0, 0, 0);
        }

        // ---- exp (no max-sub), P -> LDS (wave-local region) ----
        #pragma unroll
        for (int r = 0; r < 4; ++r) {
            float e = __expf(sacc[r] * SCALE);
            const int ip = qg * 16 + quad * 4 + r;
            const int j  = kg * 16 + ln15;
            const int pc = (j >> 3) ^ (ip & 7);
            Plds[ip * 64 + pc * 8 + (j & 7)] = f2b(e);
        }

        // ---- P fragment (A of 16x16x32 over the kg-pair's 32 keys):
        //      row = ln15 (q), k = quad*8+i; zero on other wave's half ----
        bf16x8 pf;
        {
            const int m  = qg * 16 + ln15;
            const int jc = kg * 2 + (quad & 1);
            u32x4 pw = *(const u32x4*)&Plds[m * 64 + (jc ^ (m & 7)) * 8];
            u32x4 pz = live ? pw : u32x4{0u, 0u, 0u, 0u};
            pf = __builtin_bit_cast(bf16x8, pz);
        }

        // ---- denominator: row-sum of P via ones-fragment MFMA ----
        dacc = __builtin_amdgcn_mfma_f32_16x16x32_bf16(pf, onesf, dacc, 0, 0, 0);

        // ---- PV: ctx[q][c] partial over this wave's 16 j ----
        #pragma unroll
        for (int ct = 0; ct < 16; ++ct) {
            const int c  = ct * 16 + ln15;
            const int pv = (kp * 4 + quad) ^ (c & 7);
            bf16x8 vb = __builtin_bit_cast(bf16x8,
                          *(const u32x4*)&Vd[c * 64 + pv * 8]);
            ctx[ct] = __builtin_amdgcn_mfma_f32_16x16x32_bf16(
                          pf, vb, ctx[ct], 0, 0, 0);
        }

        __syncthreads();   // drains prefetch vmcnt + guards buffer reuse
    }

    // ---- epilogue: combine 4 kg quarters, normalize, residual, store ----
    if (ln15 == 0) {
        #pragma unroll
        for (int r = 0; r < 4; ++r)
            denomP[kg * 64 + qg * 16 + quad * 4 + r] = dacc[r];
    }
    if (kg == 3) {
        #pragma unroll
        for (int ct = 0; ct < 16; ++ct) {
            const int c = ct * 16 + ln15;
            #pragma unroll
            for (int r = 0; r < 4; ++r)
                bufA[c][qg * 16 + quad * 4 + r] = ctx[ct][r];
        }
    }
    if (kg == 2) {
        #pragma unroll
        for (int ct = 0; ct < 16; ++ct) {
            const int c = ct * 16 + ln15;
            #pragma unroll
            for (int r = 0; r < 4; ++r)
                bufB[c][qg * 16 + quad * 4 + r] = ctx[ct][r];
        }
    }
    __syncthreads();
    if (kg == 1) {
        #pragma unroll
        for (int ct = 0; ct < 16; ++ct) {
            const int c = ct * 16 + ln15;
            #pragma unroll
            for (int r = 0; r < 4; ++r)
                bufA[c][qg * 16 + quad * 4 + r] += ctx[ct][r];
        }
    }
    __syncthreads();
    if (kg == 0) {
        float rinv[4];
        #pragma unroll
        for (int r = 0; r < 4; ++r) {
            const int ql = qg * 16 + quad * 4 + r;
            rinv[r] = 1.0f / (denomP[ql] + denomP[64 + ql] +
                              denomP[128 + ql] + denomP[192 + ql]);
        }
        #pragma unroll
        for (int ct = 0; ct < 16; ++ct) {
            const int c = ct * 16 + ln15;
            #pragma unroll
            for (int r = 0; r < 4; ++r) {
                const int ql = qg * 16 + quad * 4 + r;
                bufA[c][ql] = (ctx[ct][r] + bufA[c][ql] + bufB[c][ql]) * rinv[r];
            }
        }
    }
    __syncthreads();

    #pragma unroll
    for (int p = 0; p < 4; ++p) {
        const int f  = t + 1024 * p;      // 0..4095
        const int c  = f >> 4;
        const int lg = (f & 15) * 4;
        const size_t idx = ((size_t)(b * NC + c)) * NL + l0 + lg;
        float4 xv = *(const float4*)&x[idx];
        float4 cv = *(const float4*)&bufA[c][lg];
        float4 o = make_float4(cv.x + xv.x, cv.y + xv.y, cv.z + xv.z, cv.w + xv.w);
        *(float4*)&out[idx] = o;
    }
}

// ---------------------------------------------------------------------------
extern "C" void kernel_launch(void* const* d_in, const int* in_sizes, int n_in,
                              void* d_out, int out_size, void* d_ws, size_t ws_size,
                              hipStream_t stream) {
    const float* x  = (const float*)d_in[0];
    const float* Wq = (const float*)d_in[1];
    const float* bq = (const float*)d_in[2];
    const float* Wk = (const float*)d_in[3];
    const float* bk = (const float*)d_in[4];
    const float* Wv = (const float*)d_in[5];
    const float* bv = (const float*)d_in[6];
    float* out = (float*)d_out;

    const size_t plane = (size_t)NB * NC * NL;       // 4.19M elems
    unsigned short* qT  = (unsigned short*)d_ws;
    unsigned short* kT  = qT + plane;
    unsigned short* v   = kT + plane;
    unsigned short* xT  = v + plane;
    unsigned short* Wbf = xT + plane;                // 3*65536 elems

    wconv_kernel<<<192, 256, 0, stream>>>(Wq, Wk, Wv, Wbf);

    dim3 gx(NL / 64, NC / 64, NB);                   // (32, 4, 8)
    xprep_kernel<<<gx, 256, 0, stream>>>(x, xT);

    qkv_mfma<<<768, 256, 0, stream>>>(xT, Wbf, bq, bk, bv, qT, kT, v);

    attn_kernel<<<256, 1024, 0, stream>>>(qT, kT, v, x, out);
}

// Round 3
// 154.150 us; speedup vs baseline: 1.5325x; 1.5325x over previous
//
#include <hip/hip_runtime.h>

#define NB 8
#define NC 256
#define NL 2048
#define SCALE 0.0625f   // C^-0.5 = 1/16

typedef __attribute__((ext_vector_type(8))) __bf16 bf16x8;
typedef __attribute__((ext_vector_type(4))) float f32x4;
typedef __attribute__((ext_vector_type(4))) unsigned int u32x4;
typedef __attribute__((ext_vector_type(2))) unsigned int u32x2;
typedef __attribute__((ext_vector_type(4))) unsigned short u16x4;
typedef __attribute__((ext_vector_type(8))) unsigned short u16x8;

// round-to-nearest-even fp32 -> bf16 bits
static __device__ __forceinline__ unsigned short f2b(float f) {
    unsigned int u = __builtin_bit_cast(unsigned int, f);
    u += 0x7fffu + ((u >> 16) & 1u);
    return (unsigned short)(u >> 16);
}

// ---------------------------------------------------------------------------
// Prep A: Wq/Wk/Wv fp32 -> bf16, concatenated [3][256][256].
// ---------------------------------------------------------------------------
__global__ void wconv_kernel(const float* __restrict__ Wq,
                             const float* __restrict__ Wk,
                             const float* __restrict__ Wv,
                             unsigned short* __restrict__ Wbf)
{
    const int base = (blockIdx.x * 256 + threadIdx.x) * 4;
    const int mat  = base >> 16;
    const int off  = base & 65535;
    const float* W = (mat == 0) ? Wq : (mat == 1) ? Wk : Wv;
    float4 w = *(const float4*)&W[off];
    u16x4 p = {f2b(w.x), f2b(w.y), f2b(w.z), f2b(w.w)};
    *(u16x4*)&Wbf[base] = p;
}

// ---------------------------------------------------------------------------
// Prep B: x [B][C][L] fp32 -> xT [B][L][C] bf16 (transpose via LDS).
// ---------------------------------------------------------------------------
__global__ __launch_bounds__(256, 2) void xprep_kernel(
    const float* __restrict__ x, unsigned short* __restrict__ xT)
{
    const int b  = blockIdx.z;
    const int c0 = blockIdx.y * 64;
    const int l0 = blockIdx.x * 64;
    const int t  = threadIdx.x;

    __shared__ unsigned short Tr[64][68];

    #pragma unroll
    for (int p = 0; p < 4; ++p) {
        const int c  = p * 16 + (t >> 4);
        const int lg = t & 15;
        float4 xv = *(const float4*)&x[((size_t)(b * NC + c0 + c)) * NL + l0 + lg * 4];
        u16x4 pk = {f2b(xv.x), f2b(xv.y), f2b(xv.z), f2b(xv.w)};
        *(u16x4*)&Tr[c][lg * 4] = pk;
    }
    __syncthreads();
    #pragma unroll
    for (int j = 0; j < 2; ++j) {
        const int chunk = t + 256 * j;      // 0..511
        const int l  = chunk >> 3;
        const int ck = chunk & 7;
        u16x8 o;
        #pragma unroll
        for (int i = 0; i < 8; ++i) o[i] = Tr[ck * 8 + i][l];
        *(u16x8*)&xT[((size_t)(b * NL + l0 + l)) * NC + c0 + ck * 8] = o;
    }
}

// ---------------------------------------------------------------------------
// Kernel 1: QKV projection via MFMA (verbatim from verified state).
// ---------------------------------------------------------------------------
__global__ __launch_bounds__(256, 2) void qkv_mfma(
    const unsigned short* __restrict__ xT,
    const unsigned short* __restrict__ Wbf,
    const float* __restrict__ bq, const float* __restrict__ bk,
    const float* __restrict__ bv,
    unsigned short* __restrict__ qT, unsigned short* __restrict__ kT,
    unsigned short* __restrict__ vo)
{
    const int raw = blockIdx.x;
    const int b   = raw & 7;          // XCD-pinned batch
    const int rem = raw >> 3;         // 0..95
    const int mat = rem >> 5;         // 0..2
    const int lt0 = (rem & 31) * 64;
    const int t    = threadIdx.x;
    const int w    = t >> 6;
    const int lane = t & 63;
    const int ln15 = lane & 15;
    const int quad = lane >> 4;

    __shared__ __align__(16) unsigned short XT[64 * 256];  // [l][c] swz, 32 KB
    __shared__ __align__(16) unsigned short WC[256 * 64];  // [o][c-chunk] swz, 32 KB

    const unsigned short* Wm = Wbf + mat * 65536;
    const float* bias = (mat == 0) ? bq : (mat == 1) ? bk : bv;

    float bvals[4][4];
    #pragma unroll
    for (int ot = 0; ot < 4; ++ot)
        #pragma unroll
        for (int r = 0; r < 4; ++r)
            bvals[ot][r] = bias[w * 64 + ot * 16 + quad * 4 + r];

    #pragma unroll
    for (int s = 0; s < 8; ++s) {
        const int il = w * 8 + s;
        const int n  = il * 2 + (lane >> 5);
        const int p  = lane & 31;
        const int g  = p ^ (n & 15);
        const unsigned short* gp = &xT[((size_t)(b * NL + lt0 + n)) * NC + g * 8];
        __builtin_amdgcn_global_load_lds(
            (const __attribute__((address_space(1))) unsigned int*)gp,
            (__attribute__((address_space(3))) unsigned int*)&XT[il * 512],
            16, 0, 0);
    }

    f32x4 acc[4][4];
    #pragma unroll
    for (int i = 0; i < 4; ++i)
        #pragma unroll
        for (int j = 0; j < 4; ++j) acc[i][j] = f32x4{0.f, 0.f, 0.f, 0.f};

    for (int k0 = 0; k0 < 4; ++k0) {
        if (k0) __syncthreads();
        #pragma unroll
        for (int s = 0; s < 8; ++s) {
            const int il = w * 8 + s;
            const int o  = il * 8 + (lane >> 3);
            const int p  = lane & 7;
            const int g  = p ^ (o & 7);
            const unsigned short* gp = &Wm[(size_t)o * NC + k0 * 64 + g * 8];
            __builtin_amdgcn_global_load_lds(
                (const __attribute__((address_space(1))) unsigned int*)gp,
                (__attribute__((address_space(3))) unsigned int*)&WC[il * 512],
                16, 0, 0);
        }
        __syncthreads();

        #pragma unroll
        for (int ks = 0; ks < 2; ++ks) {
            bf16x8 xf[4];
            #pragma unroll
            for (int lt = 0; lt < 4; ++lt) {
                const int l  = lt * 16 + ln15;
                const int kc = k0 * 8 + ks * 4 + quad;
                const int pp = kc ^ (l & 15);
                xf[lt] = __builtin_bit_cast(bf16x8, *(const u32x4*)&XT[l * 256 + pp * 8]);
            }
            #pragma unroll
            for (int ot = 0; ot < 4; ++ot) {
                const int o  = w * 64 + ot * 16 + ln15;
                const int pp = (ks * 4 + quad) ^ (o & 7);
                bf16x8 wf = __builtin_bit_cast(bf16x8, *(const u32x4*)&WC[o * 64 + pp * 8]);
                #pragma unroll
                for (int lt = 0; lt < 4; ++lt)
                    acc[ot][lt] = __builtin_amdgcn_mfma_f32_16x16x32_bf16(
                                      wf, xf[lt], acc[ot][lt], 0, 0, 0);
            }
        }
    }

    if (mat < 2) {
        unsigned short* out = (mat == 0) ? qT : kT;
        #pragma unroll
        for (int ot = 0; ot < 4; ++ot) {
            const int o_base = w * 64 + ot * 16 + quad * 4;
            #pragma unroll
            for (int lt = 0; lt < 4; ++lt) {
                const int l = lt0 + lt * 16 + ln15;
                u16x4 pk;
                #pragma unroll
                for (int r = 0; r < 4; ++r)
                    pk[r] = f2b(acc[ot][lt][r] + bvals[ot][r]);
                *(u16x4*)&out[((size_t)(b * NL + l)) * NC + o_base] = pk;
            }
        }
    } else {
        #pragma unroll
        for (int ot = 0; ot < 4; ++ot)
            #pragma unroll
            for (int lt = 0; lt < 4; ++lt) {
                const int l = lt0 + lt * 16 + ln15;
                #pragma unroll
                for (int r = 0; r < 4; ++r) {
                    const int o = w * 64 + ot * 16 + quad * 4 + r;
                    vo[((size_t)(b * NC + o)) * NL + l] = f2b(acc[ot][lt][r] + bvals[ot][r]);
                }
            }
    }
}

// ---------------------------------------------------------------------------
// Kernel 2: MFMA flash attention + residual.
// grid 256 (b=raw&7, 32 l-tiles), block 1024 = 16 waves (qg 0..3 x kg 0..3)
// -> 4 waves/SIMD. Per tile:
//   QK (key-split):  wave (qg,kg) computes S^T for its 16 keys via SWAPPED
//                    MFMA (A=K, B=Q) -> lane holds P[key=kg*16+quad*4+r]
//                    [q=qg*16+ln15]: 4 consecutive keys, one ds_write_b64
//                    into swizzled P[64q][64k].
//   mid barrier:     raw s_barrier + lgkmcnt(0) only (NO vmcnt drain ->
//                    dbuf prefetch stays in flight across it).
//   PV (chan-split): wave (qg,kg) computes ctx for its 16 q-rows x 64
//                    channels (c = kg*64..) with K=64 over the FULL tile:
//                    2 P A-frags (b128) x 4 ch-tiles. ctx[4] = 16 VGPRs.
//   denom:           2 ones-MFMAs on the same P A-frags; D-row layout
//                    matches ctx -> fully in-register normalization,
//                    NO cross-wave combine epilogue.
// ---------------------------------------------------------------------------
__global__ __launch_bounds__(1024, 4) void attn_kernel(
    const unsigned short* __restrict__ qT,
    const unsigned short* __restrict__ kT,
    const unsigned short* __restrict__ v,
    const float* __restrict__ x,
    float* __restrict__ out)
{
    const int raw  = blockIdx.x;
    const int b    = raw & 7;         // XCD-pinned batch
    const int l0   = (raw >> 3) * 64;
    const int t    = threadIdx.x;
    const int w    = t >> 6;          // 0..15
    const int lane = t & 63;
    const int ln15 = lane & 15;
    const int quad = lane >> 4;
    const int qg   = w & 3;           // query group (16 rows)
    const int kg   = w >> 2;          // key quarter (QK) / channel quarter (PV)

    __shared__ __align__(16) char smem[139264];
    unsigned short* Kb0 = (unsigned short*)smem;             // 32 KB
    unsigned short* Kb1 = (unsigned short*)(smem + 32768);   // 32 KB
    unsigned short* Vb0 = (unsigned short*)(smem + 65536);   // 32 KB
    unsigned short* Vb1 = (unsigned short*)(smem + 98304);   // 32 KB
    char* Plds = smem + 131072;                              //  8 KB [64q][64k] swz
    float (*buf)[68] = (float(*)[68])smem;                   // epilogue alias 69.6 KB

    // ---- Q fragments resident: rows l0 + qg*16 + ln15 (B-operand layout) ----
    bf16x8 qf[8];
    {
        const size_t qrow = ((size_t)b * NL + l0 + qg * 16 + ln15) * NC;
        #pragma unroll
        for (int kt = 0; kt < 8; ++kt)
            qf[kt] = __builtin_bit_cast(bf16x8,
                        *(const u32x4*)&qT[qrow + kt * 32 + quad * 8]);
    }

    f32x4 ctx[4];
    #pragma unroll
    for (int i = 0; i < 4; ++i) ctx[i] = f32x4{0.f, 0.f, 0.f, 0.f};
    f32x4 dacc = f32x4{0.f, 0.f, 0.f, 0.f};

    const u16x8 ones_u = {0x3F80, 0x3F80, 0x3F80, 0x3F80,
                          0x3F80, 0x3F80, 0x3F80, 0x3F80};
    const bf16x8 onesf = __builtin_bit_cast(bf16x8, ones_u);

    auto stage = [&](int mt, unsigned short* Kd, unsigned short* Vd) {
        const int m0 = mt * 64;
        #pragma unroll
        for (int s = 0; s < 2; ++s) {
            const int il = w * 2 + s;
            const int n  = il * 2 + (lane >> 5);
            const int g  = (lane & 31) ^ (n & 15);
            const unsigned short* gp = &kT[((size_t)b * NL + m0 + n) * NC + g * 8];
            __builtin_amdgcn_global_load_lds(
                (const __attribute__((address_space(1))) unsigned int*)gp,
                (__attribute__((address_space(3))) unsigned int*)&Kd[il * 512],
                16, 0, 0);
        }
        #pragma unroll
        for (int s = 0; s < 2; ++s) {
            const int il = w * 2 + s;
            const int c  = il * 8 + (lane >> 3);
            const int g  = (lane & 7) ^ (c & 7);
            const unsigned short* gp = &v[((size_t)(b * NC + c)) * NL + m0 + g * 8];
            __builtin_amdgcn_global_load_lds(
                (const __attribute__((address_space(1))) unsigned int*)gp,
                (__attribute__((address_space(3))) unsigned int*)&Vd[il * 512],
                16, 0, 0);
        }
    };

    stage(0, Kb0, Vb0);
    __syncthreads();   // buf0 ready

    const int q    = qg * 16 + ln15;           // this lane's q row (QK col / PV row base)
    const int pwof = q * 128 + (((kg * 32) + quad * 8) ^ ((q & 7) << 4));
    int prof[2];
    #pragma unroll
    for (int jw = 0; jw < 2; ++jw)
        prof[jw] = q * 128 + ((jw * 64 + quad * 16) ^ ((q & 7) << 4));

    for (int mt = 0; mt < 32; ++mt) {
        // prefetch next tile into the other buffer (overlaps compute below)
        if (mt < 31) {
            if (mt & 1) stage(mt + 1, Kb0, Vb0);
            else        stage(mt + 1, Kb1, Vb1);
        }
        const unsigned short* Kd = (mt & 1) ? Kb1 : Kb0;
        const unsigned short* Vd = (mt & 1) ? Vb1 : Vb0;

        // ---- swapped QK: S^T = K Q^T. A=K rows (this wave's 16 keys),
        //      B=Q cols. Lane -> P[key=kg*16+quad*4+r][q]. ----
        f32x4 sacc = f32x4{0.f, 0.f, 0.f, 0.f};
        {
            const int n = kg * 16 + ln15;      // key row in Kd
            #pragma unroll
            for (int kt = 0; kt < 8; ++kt) {
                const int p = (kt * 4 + quad) ^ (n & 15);
                bf16x8 kf = __builtin_bit_cast(bf16x8,
                              *(const u32x4*)&Kd[n * 256 + p * 8]);
                sacc = __builtin_amdgcn_mfma_f32_16x16x32_bf16(
                           kf, qf[kt], sacc, 0, 0, 0);
            }
        }

        // ---- exp (no max-sub), pack 4 consecutive keys, 1 ds_write_b64 ----
        {
            float e0 = __expf(sacc[0] * SCALE);
            float e1 = __expf(sacc[1] * SCALE);
            float e2 = __expf(sacc[2] * SCALE);
            float e3 = __expf(sacc[3] * SCALE);
            unsigned int d0 = (unsigned int)f2b(e0) | ((unsigned int)f2b(e1) << 16);
            unsigned int d1 = (unsigned int)f2b(e2) | ((unsigned int)f2b(e3) << 16);
            *(u32x2*)(Plds + pwof) = u32x2{d0, d1};
        }

        // ---- mid barrier: P visible; lgkm only (prefetch vmcnt stays hot) ----
        asm volatile("s_waitcnt lgkmcnt(0)" ::: "memory");
        __builtin_amdgcn_s_barrier();
        __builtin_amdgcn_sched_barrier(0);

        // ---- P A-frags: row=q, k=jw*32+quad*8+i (full 64-key tile) ----
        bf16x8 pa[2];
        #pragma unroll
        for (int jw = 0; jw < 2; ++jw)
            pa[jw] = __builtin_bit_cast(bf16x8, *(const u32x4*)(Plds + prof[jw]));

        // ---- denominator: row-sum of P via ones MFMA (D rows match ctx) ----
        dacc = __builtin_amdgcn_mfma_f32_16x16x32_bf16(pa[0], onesf, dacc, 0, 0, 0);
        dacc = __builtin_amdgcn_mfma_f32_16x16x32_bf16(pa[1], onesf, dacc, 0, 0, 0);

        // ---- PV channel-split: channels kg*64 + ct*16 + ln15, K=64 ----
        #pragma unroll
        for (int ct = 0; ct < 4; ++ct) {
            const int c = kg * 64 + ct * 16 + ln15;
            #pragma unroll
            for (int jw = 0; jw < 2; ++jw) {
                const int p = (jw * 4 + quad) ^ (c & 7);
                bf16x8 vb = __builtin_bit_cast(bf16x8,
                              *(const u32x4*)&Vd[c * 64 + p * 8]);
                ctx[ct] = __builtin_amdgcn_mfma_f32_16x16x32_bf16(
                              pa[jw], vb, ctx[ct], 0, 0, 0);
            }
        }

        __syncthreads();   // end of tile: drains prefetch, guards K/V + P reuse
    }

    // ---- epilogue: in-register normalize, stage to LDS, residual, store ----
    {
        float rinv[4];
        #pragma unroll
        for (int r = 0; r < 4; ++r) rinv[r] = 1.0f / dacc[r];
        #pragma unroll
        for (int ct = 0; ct < 4; ++ct) {
            const int c = kg * 64 + ct * 16 + ln15;
            #pragma unroll
            for (int r = 0; r < 4; ++r)
                buf[c][qg * 16 + quad * 4 + r] = ctx[ct][r] * rinv[r];
        }
    }
    __syncthreads();

    #pragma unroll
    for (int p = 0; p < 4; ++p) {
        const int f  = t + 1024 * p;      // 0..4095
        const int c  = f >> 4;
        const int lg = (f & 15) * 4;
        const size_t idx = ((size_t)(b * NC + c)) * NL + l0 + lg;
        float4 xv = *(const float4*)&x[idx];
        float4 cv = *(const float4*)&buf[c][lg];
        float4 o = make_float4(cv.x + xv.x, cv.y + xv.y, cv.z + xv.z, cv.w + xv.w);
        *(float4*)&out[idx] = o;
    }
}

// ---------------------------------------------------------------------------
extern "C" void kernel_launch(void* const* d_in, const int* in_sizes, int n_in,
                              void* d_out, int out_size, void* d_ws, size_t ws_size,
                              hipStream_t stream) {
    const float* x  = (const float*)d_in[0];
    const float* Wq = (const float*)d_in[1];
    const float* bq = (const float*)d_in[2];
    const float* Wk = (const float*)d_in[3];
    const float* bk = (const float*)d_in[4];
    const float* Wv = (const float*)d_in[5];
    const float* bv = (const float*)d_in[6];
    float* out = (float*)d_out;

    const size_t plane = (size_t)NB * NC * NL;       // 4.19M elems
    unsigned short* qT  = (unsigned short*)d_ws;
    unsigned short* kT  = qT + plane;
    unsigned short* v   = kT + plane;
    unsigned short* xT  = v + plane;
    unsigned short* Wbf = xT + plane;                // 3*65536 elems

    wconv_kernel<<<192, 256, 0, stream>>>(Wq, Wk, Wv, Wbf);

    dim3 gx(NL / 64, NC / 64, NB);                   // (32, 4, 8)
    xprep_kernel<<<gx, 256, 0, stream>>>(x, xT);

    qkv_mfma<<<768, 256, 0, stream>>>(xT, Wbf, bq, bk, bv, qT, kT, v);

    attn_kernel<<<256, 1024, 0, stream>>>(qT, kT, v, x, out);
}